// Round 1
// baseline (461.633 us; speedup 1.0000x reference)
//
#include <hip/hip_runtime.h>

#define E_EDGES 1600000
#define BM 64
#define TPB 256
#define NTILES (E_EDGES / BM)   // 25000 exactly

typedef short s16x8 __attribute__((ext_vector_type(8)));
typedef float f32x4 __attribute__((ext_vector_type(4)));

__device__ __forceinline__ unsigned short f2bf(float f) {
    unsigned int u = __builtin_bit_cast(unsigned int, f);
    u += 0x7FFFu + ((u >> 16) & 1u);   // RNE
    return (unsigned short)(u >> 16);
}

__device__ __forceinline__ s16x8 pack8(float4 a, float4 b) {
    s16x8 r;
    r[0] = (short)f2bf(a.x); r[1] = (short)f2bf(a.y);
    r[2] = (short)f2bf(a.z); r[3] = (short)f2bf(a.w);
    r[4] = (short)f2bf(b.x); r[5] = (short)f2bf(b.y);
    r[6] = (short)f2bf(b.z); r[7] = (short)f2bf(b.w);
    return r;
}

// d_ws layout (bf16): [0,16384) Wnnn^T [128o][128i]; [16384,24576) Wroot^T [128o][64i];
//                     [24576,40960) Wout^T [128o][128i]
__global__ void prep_w(const float* __restrict__ Wn, const float* __restrict__ Wr,
                       const float* __restrict__ Wo, unsigned short* __restrict__ wt) {
    int t = blockIdx.x * 256 + threadIdx.x;
    if (t < 16384) {
        int o = t >> 7, i = t & 127;
        wt[t] = f2bf(Wn[i * 128 + o]);
    } else if (t < 24576) {
        int q = t - 16384;
        int o = q >> 6, i = q & 63;
        wt[t] = f2bf(Wr[i * 128 + o]);
    } else if (t < 40960) {
        int q = t - 24576;
        int o = q >> 7, i = q & 127;
        wt[t] = f2bf(Wo[i * 128 + o]);
    }
}

__global__ __launch_bounds__(TPB) void edge_mlp(
    const float* __restrict__ x, const int* __restrict__ eidx,
    const float* __restrict__ ea,
    const float* __restrict__ bn_g, const float* __restrict__ br_g,
    const float* __restrict__ bo_g,
    const unsigned short* __restrict__ wt, float* __restrict__ out)
{
    __shared__ unsigned short sh_pair[BM * 128];  // 16 KB, swizzled
    __shared__ unsigned short sh_ea[BM * 64];     //  8 KB, swizzled
    __shared__ unsigned short sh_hid[BM * 128];   // 16 KB, swizzled

    const int tid = threadIdx.x;
    const int wv  = tid >> 6;        // wave 0..3 -> N-slice
    const int ln  = tid & 63;
    const int lc  = ln & 15;         // col within 16-wide N-tile / row within M-tile
    const int lk8 = (ln >> 4) * 8;   // k sub-offset
    const int ncol = wv * 32;

    const unsigned short* Wn = wt;
    const unsigned short* Wr = wt + 16384;
    const unsigned short* Wo = wt + 24576;

    // --- per-wave weight fragments in registers, loaded once ---
    s16x8 wn[2][4], wr[2][2], wo[2][4];
    float bn[2], br[2], bo[2];
    #pragma unroll
    for (int nt = 0; nt < 2; ++nt) {
        const int n = ncol + nt * 16 + lc;
        #pragma unroll
        for (int ks = 0; ks < 4; ++ks)
            wn[nt][ks] = *(const s16x8*)(Wn + n * 128 + ks * 32 + lk8);
        #pragma unroll
        for (int ks = 0; ks < 2; ++ks)
            wr[nt][ks] = *(const s16x8*)(Wr + n * 64 + ks * 32 + lk8);
        #pragma unroll
        for (int ks = 0; ks < 4; ++ks)
            wo[nt][ks] = *(const s16x8*)(Wo + n * 128 + ks * 32 + lk8);
        bn[nt] = bn_g[n]; br[nt] = br_g[n]; bo[nt] = bo_g[n];
    }

    for (int tile = blockIdx.x; tile < NTILES; tile += gridDim.x) {
        const int base = tile * BM;

        // --- gather pair = [src | dst] -> bf16 LDS (swizzled) ---
        #pragma unroll
        for (int it = 0; it < 4; ++it) {
            int q = tid + it * TPB;          // 1024 chunks of 16B
            int r = q >> 4, c = q & 15;
            int node = (c < 8) ? eidx[base + r] : eidx[E_EDGES + base + r];
            const float4* xp = (const float4*)(x + (size_t)node * 64 + (size_t)(c & 7) * 8);
            float4 f0 = xp[0], f1 = xp[1];
            unsigned off = (unsigned)(r * 256 + c * 16) ^ (unsigned)((r & 7) << 4);
            *(s16x8*)((char*)sh_pair + off) = pack8(f0, f1);
        }
        // --- edge_attr -> bf16 LDS (swizzled) ---
        #pragma unroll
        for (int it = 0; it < 2; ++it) {
            int q = tid + it * TPB;          // 512 chunks of 16B
            int r = q >> 3, c = q & 7;
            const float4* ep = (const float4*)(ea + (size_t)(base + r) * 64 + (size_t)c * 8);
            float4 f0 = ep[0], f1 = ep[1];
            unsigned off = (unsigned)(r * 128 + c * 16) ^ (unsigned)((r & 7) << 4);
            *(s16x8*)((char*)sh_ea + off) = pack8(f0, f1);
        }
        __syncthreads();

        // --- layer 1: hidden = relu(pair@Wnnn+bn) + relu(ea@Wroot+br) ---
        #pragma unroll
        for (int m = 0; m < 4; ++m) {
            const int row = m * 16 + lc;
            f32x4 a1[2] = {{0.f,0.f,0.f,0.f},{0.f,0.f,0.f,0.f}};
            f32x4 a2[2] = {{0.f,0.f,0.f,0.f},{0.f,0.f,0.f,0.f}};
            #pragma unroll
            for (int ks = 0; ks < 4; ++ks) {
                unsigned off = (unsigned)(row * 256 + (ks * 32 + lk8) * 2) ^ (unsigned)((row & 7) << 4);
                s16x8 a = *(const s16x8*)((const char*)sh_pair + off);
                a1[0] = __builtin_amdgcn_mfma_f32_16x16x32_bf16(a, wn[0][ks], a1[0], 0, 0, 0);
                a1[1] = __builtin_amdgcn_mfma_f32_16x16x32_bf16(a, wn[1][ks], a1[1], 0, 0, 0);
            }
            #pragma unroll
            for (int ks = 0; ks < 2; ++ks) {
                unsigned off = (unsigned)(row * 128 + (ks * 32 + lk8) * 2) ^ (unsigned)((row & 7) << 4);
                s16x8 a = *(const s16x8*)((const char*)sh_ea + off);
                a2[0] = __builtin_amdgcn_mfma_f32_16x16x32_bf16(a, wr[0][ks], a2[0], 0, 0, 0);
                a2[1] = __builtin_amdgcn_mfma_f32_16x16x32_bf16(a, wr[1][ks], a2[1], 0, 0, 0);
            }
            #pragma unroll
            for (int nt = 0; nt < 2; ++nt) {
                #pragma unroll
                for (int j = 0; j < 4; ++j) {
                    float h = fmaxf(a1[nt][j] + bn[nt], 0.f) + fmaxf(a2[nt][j] + br[nt], 0.f);
                    int hr = m * 16 + (ln >> 4) * 4 + j;
                    int hc = ncol + nt * 16 + lc;
                    unsigned off = (unsigned)(hr * 256 + hc * 2) ^ (unsigned)((hr & 7) << 4);
                    *(unsigned short*)((char*)sh_hid + off) = f2bf(h);
                }
            }
        }
        __syncthreads();

        // --- layer 2: out = relu(hidden@Wout+bo) ---
        #pragma unroll
        for (int m = 0; m < 4; ++m) {
            const int row = m * 16 + lc;
            f32x4 a3[2] = {{0.f,0.f,0.f,0.f},{0.f,0.f,0.f,0.f}};
            #pragma unroll
            for (int ks = 0; ks < 4; ++ks) {
                unsigned off = (unsigned)(row * 256 + (ks * 32 + lk8) * 2) ^ (unsigned)((row & 7) << 4);
                s16x8 a = *(const s16x8*)((const char*)sh_hid + off);
                a3[0] = __builtin_amdgcn_mfma_f32_16x16x32_bf16(a, wo[0][ks], a3[0], 0, 0, 0);
                a3[1] = __builtin_amdgcn_mfma_f32_16x16x32_bf16(a, wo[1][ks], a3[1], 0, 0, 0);
            }
            #pragma unroll
            for (int nt = 0; nt < 2; ++nt) {
                #pragma unroll
                for (int j = 0; j < 4; ++j) {
                    float o = fmaxf(a3[nt][j] + bo[nt], 0.f);
                    int orow = base + m * 16 + (ln >> 4) * 4 + j;
                    out[(size_t)orow * 128 + (size_t)(ncol + nt * 16 + lc)] = o;
                }
            }
        }
        // no end-of-loop barrier needed: next gather only writes sh_pair/sh_ea,
        // whose readers all passed the mid-tile barrier; layer-2's sh_hid reads
        // are protected by the next iteration's post-gather barrier.
    }
}

extern "C" void kernel_launch(void* const* d_in, const int* in_sizes, int n_in,
                              void* d_out, int out_size, void* d_ws, size_t ws_size,
                              hipStream_t stream) {
    const float* x   = (const float*)d_in[0];
    const int*   ei  = (const int*)d_in[1];
    const float* ea  = (const float*)d_in[2];
    const float* Wn  = (const float*)d_in[3];
    const float* bn  = (const float*)d_in[4];
    const float* Wr  = (const float*)d_in[5];
    const float* br  = (const float*)d_in[6];
    const float* Wo  = (const float*)d_in[7];
    const float* bo  = (const float*)d_in[8];
    float* out = (float*)d_out;
    unsigned short* wt = (unsigned short*)d_ws;

    prep_w<<<160, 256, 0, stream>>>(Wn, Wr, Wo, wt);
    edge_mlp<<<2048, TPB, 0, stream>>>(x, ei, ea, bn, br, bo, wt, out);
}

// Round 2
// 363.127 us; speedup vs baseline: 1.2713x; 1.2713x over previous
//
#include <hip/hip_runtime.h>

#define E_EDGES 1600000
#define BM 64
#define TPB 256
#define NTILES (E_EDGES / BM)   // 25000 exactly
#define GRID 2048

typedef short s16x8 __attribute__((ext_vector_type(8)));
typedef float f32x4 __attribute__((ext_vector_type(4)));

__device__ __forceinline__ unsigned short f2bf(float f) {
    unsigned int u = __builtin_bit_cast(unsigned int, f);
    u += 0x7FFFu + ((u >> 16) & 1u);   // RNE
    return (unsigned short)(u >> 16);
}

__device__ __forceinline__ s16x8 pack8(float4 a, float4 b) {
    s16x8 r;
    r[0] = (short)f2bf(a.x); r[1] = (short)f2bf(a.y);
    r[2] = (short)f2bf(a.z); r[3] = (short)f2bf(a.w);
    r[4] = (short)f2bf(b.x); r[5] = (short)f2bf(b.y);
    r[6] = (short)f2bf(b.z); r[7] = (short)f2bf(b.w);
    return r;
}

// d_ws layout (bf16): [0,16384) Wnnn^T [128o][128i]; [16384,24576) Wroot^T [128o][64i];
//                     [24576,40960) Wout^T [128o][128i]
__global__ void prep_w(const float* __restrict__ Wn, const float* __restrict__ Wr,
                       const float* __restrict__ Wo, unsigned short* __restrict__ wt) {
    int t = blockIdx.x * 256 + threadIdx.x;
    if (t < 16384) {
        int o = t >> 7, i = t & 127;
        wt[t] = f2bf(Wn[i * 128 + o]);
    } else if (t < 24576) {
        int q = t - 16384;
        int o = q >> 6, i = q & 63;
        wt[t] = f2bf(Wr[i * 128 + o]);
    } else if (t < 40960) {
        int q = t - 24576;
        int o = q >> 7, i = q & 127;
        wt[t] = f2bf(Wo[i * 128 + o]);
    }
}

__global__ __launch_bounds__(TPB) void edge_mlp(
    const float* __restrict__ x, const int* __restrict__ eidx,
    const float* __restrict__ ea,
    const float* __restrict__ bn_g, const float* __restrict__ br_g,
    const float* __restrict__ bo_g,
    const unsigned short* __restrict__ wt, float* __restrict__ out)
{
    __shared__ unsigned short sh_pair[BM * 128];  // 16 KB, swizzled
    __shared__ unsigned short sh_ea[BM * 64];     //  8 KB, swizzled
    __shared__ unsigned short sh_hid[BM * 128];   // 16 KB, swizzled

    const int tid = threadIdx.x;
    const int wv  = tid >> 6;        // wave 0..3 -> N-slice
    const int ln  = tid & 63;
    const int lc  = ln & 15;
    const int lk8 = (ln >> 4) * 8;
    const int ncol = wv * 32;

    // gather ownership: thread covers edge-row r, quarter `sub` of the pair row
    const int r   = tid >> 2;        // 0..63
    const int sub = tid & 3;         // 0,1: src halves; 2,3: dst halves
    const int idx_base = (sub < 2) ? 0 : E_EDGES;
    const int xoff = (sub & 1) * 32; // float offset within node row

    const unsigned short* Wn = wt;
    const unsigned short* Wr = wt + 16384;
    const unsigned short* Wo = wt + 24576;

    // --- per-wave weight fragments in registers, loaded once ---
    s16x8 wn[2][4], wr[2][2], wo[2][4];
    float bn[2], br[2], bo[2];
    #pragma unroll
    for (int nt = 0; nt < 2; ++nt) {
        const int n = ncol + nt * 16 + lc;
        #pragma unroll
        for (int ks = 0; ks < 4; ++ks)
            wn[nt][ks] = *(const s16x8*)(Wn + n * 128 + ks * 32 + lk8);
        #pragma unroll
        for (int ks = 0; ks < 2; ++ks)
            wr[nt][ks] = *(const s16x8*)(Wr + n * 64 + ks * 32 + lk8);
        #pragma unroll
        for (int ks = 0; ks < 4; ++ks)
            wo[nt][ks] = *(const s16x8*)(Wo + n * 128 + ks * 32 + lk8);
        bn[nt] = bn_g[n]; br[nt] = br_g[n]; bo[nt] = bo_g[n];
    }

    // --- software pipeline state: tile t+1's data in flight during tile t ---
    float4 pp[8];   // 128B contiguous slice of x[node]
    float4 pe[4];   // 64B slice of edge_attr row
    int idx_n, idx_nn;

    int tile = blockIdx.x;
    if (tile >= NTILES) return;

    idx_n = eidx[idx_base + tile * BM + r];
    {   // issue tile-0 loads
        const float4* xp = (const float4*)(x + (size_t)idx_n * 64 + xoff);
        #pragma unroll
        for (int k = 0; k < 8; ++k) pp[k] = xp[k];
        const float4* ep = (const float4*)(ea + (size_t)(tile * BM + r) * 64 + sub * 16);
        #pragma unroll
        for (int k = 0; k < 4; ++k) pe[k] = ep[k];
    }
    {   // prefetch tile-1's index (breaks idx->gather dependent chain)
        int t1 = (tile + GRID < NTILES) ? tile + GRID : tile;
        idx_nn = eidx[idx_base + t1 * BM + r];
    }

    for (; tile < NTILES; tile += GRID) {
        const int base = tile * BM;
        const int tn  = (tile + GRID < NTILES) ? tile + GRID : tile;

        // --- 1. drain prefetch -> bf16 LDS (swizzled) ---
        #pragma unroll
        for (int it = 0; it < 4; ++it) {
            int c = 4 * sub + it;
            unsigned off = (unsigned)(r * 256 + c * 16) ^ (unsigned)((r & 7) << 4);
            *(s16x8*)((char*)sh_pair + off) = pack8(pp[2 * it], pp[2 * it + 1]);
        }
        #pragma unroll
        for (int it = 0; it < 2; ++it) {
            int c = 2 * sub + it;
            unsigned off = (unsigned)(r * 128 + c * 16) ^ (unsigned)((r & 7) << 4);
            *(s16x8*)((char*)sh_ea + off) = pack8(pe[2 * it], pe[2 * it + 1]);
        }

        // --- 2. issue next tile's loads (latency hidden under compute) ---
        idx_n = idx_nn;
        {
            const float4* xp = (const float4*)(x + (size_t)idx_n * 64 + xoff);
            #pragma unroll
            for (int k = 0; k < 8; ++k) pp[k] = xp[k];
            const float4* ep = (const float4*)(ea + (size_t)(tn * BM + r) * 64 + sub * 16);
            #pragma unroll
            for (int k = 0; k < 4; ++k) pe[k] = ep[k];
        }
        {
            int tnn = (tn + GRID < NTILES) ? tn + GRID : tn;
            idx_nn = eidx[idx_base + tnn * BM + r];
        }
        __syncthreads();

        // --- 3. layer 1: hidden = relu(pair@Wnnn+bn) + relu(ea@Wroot+br) ---
        #pragma unroll
        for (int m = 0; m < 4; ++m) {
            const int row = m * 16 + lc;
            f32x4 a1[2] = {{0.f,0.f,0.f,0.f},{0.f,0.f,0.f,0.f}};
            f32x4 a2[2] = {{0.f,0.f,0.f,0.f},{0.f,0.f,0.f,0.f}};
            #pragma unroll
            for (int ks = 0; ks < 4; ++ks) {
                unsigned off = (unsigned)(row * 256 + (ks * 32 + lk8) * 2) ^ (unsigned)((row & 7) << 4);
                s16x8 a = *(const s16x8*)((const char*)sh_pair + off);
                a1[0] = __builtin_amdgcn_mfma_f32_16x16x32_bf16(a, wn[0][ks], a1[0], 0, 0, 0);
                a1[1] = __builtin_amdgcn_mfma_f32_16x16x32_bf16(a, wn[1][ks], a1[1], 0, 0, 0);
            }
            #pragma unroll
            for (int ks = 0; ks < 2; ++ks) {
                unsigned off = (unsigned)(row * 128 + (ks * 32 + lk8) * 2) ^ (unsigned)((row & 7) << 4);
                s16x8 a = *(const s16x8*)((const char*)sh_ea + off);
                a2[0] = __builtin_amdgcn_mfma_f32_16x16x32_bf16(a, wr[0][ks], a2[0], 0, 0, 0);
                a2[1] = __builtin_amdgcn_mfma_f32_16x16x32_bf16(a, wr[1][ks], a2[1], 0, 0, 0);
            }
            #pragma unroll
            for (int nt = 0; nt < 2; ++nt) {
                #pragma unroll
                for (int j = 0; j < 4; ++j) {
                    float h = fmaxf(a1[nt][j] + bn[nt], 0.f) + fmaxf(a2[nt][j] + br[nt], 0.f);
                    int hr = m * 16 + (ln >> 4) * 4 + j;
                    int hc = ncol + nt * 16 + lc;
                    unsigned off = (unsigned)(hr * 256 + hc * 2) ^ (unsigned)((hr & 7) << 4);
                    *(unsigned short*)((char*)sh_hid + off) = f2bf(h);
                }
            }
        }
        __syncthreads();

        // --- 4. layer 2: out = relu(hidden@Wout+bo) ---
        #pragma unroll
        for (int m = 0; m < 4; ++m) {
            const int row = m * 16 + lc;
            f32x4 a3[2] = {{0.f,0.f,0.f,0.f},{0.f,0.f,0.f,0.f}};
            #pragma unroll
            for (int ks = 0; ks < 4; ++ks) {
                unsigned off = (unsigned)(row * 256 + (ks * 32 + lk8) * 2) ^ (unsigned)((row & 7) << 4);
                s16x8 a = *(const s16x8*)((const char*)sh_hid + off);
                a3[0] = __builtin_amdgcn_mfma_f32_16x16x32_bf16(a, wo[0][ks], a3[0], 0, 0, 0);
                a3[1] = __builtin_amdgcn_mfma_f32_16x16x32_bf16(a, wo[1][ks], a3[1], 0, 0, 0);
            }
            #pragma unroll
            for (int nt = 0; nt < 2; ++nt) {
                #pragma unroll
                for (int j = 0; j < 4; ++j) {
                    float o = fmaxf(a3[nt][j] + bo[nt], 0.f);
                    int orow = base + m * 16 + (ln >> 4) * 4 + j;
                    out[(size_t)orow * 128 + (size_t)(ncol + nt * 16 + lc)] = o;
                }
            }
        }
        // barrier discipline: next iter's sh_pair/sh_ea writes are ordered after
        // all L1 reads by the mid-tile barrier of THIS iter; sh_hid writes of
        // next L1 are ordered after these L2 reads by next iter's post-gather
        // barrier. 2 barriers/tile total.
    }
}

extern "C" void kernel_launch(void* const* d_in, const int* in_sizes, int n_in,
                              void* d_out, int out_size, void* d_ws, size_t ws_size,
                              hipStream_t stream) {
    const float* x   = (const float*)d_in[0];
    const int*   ei  = (const int*)d_in[1];
    const float* ea  = (const float*)d_in[2];
    const float* Wn  = (const float*)d_in[3];
    const float* bn  = (const float*)d_in[4];
    const float* Wr  = (const float*)d_in[5];
    const float* br  = (const float*)d_in[6];
    const float* Wo  = (const float*)d_in[7];
    const float* bo  = (const float*)d_in[8];
    float* out = (float*)d_out;
    unsigned short* wt = (unsigned short*)d_ws;

    prep_w<<<160, 256, 0, stream>>>(Wn, Wr, Wo, wt);
    edge_mlp<<<GRID, TPB, 0, stream>>>(x, ei, ea, bn, br, bo, wt, out);
}